// Round 3
// baseline (108.040 us; speedup 1.0000x reference)
//
#include <hip/hip_runtime.h>

#define NQ 10
#define QD 6
#define DIN 512
#define DOUT 64

typedef float v2f __attribute__((ext_vector_type(2)));

__device__ __forceinline__ v2f mk2(float a, float b) { v2f r; r.x = a; r.y = b; return r; }
__device__ __forceinline__ v2f swap2(v2f v) { return mk2(v.y, v.x); }
#if __has_builtin(__builtin_elementwise_fma)
__device__ __forceinline__ v2f pkfma(v2f a, v2f b, v2f c) { return __builtin_elementwise_fma(a, b, c); }
#else
__device__ __forceinline__ v2f pkfma(v2f a, v2f b, v2f c) {
    return mk2(fmaf(a.x, b.x, c.x), fmaf(a.y, b.y, c.y));
}
#endif

// All cross-lane via compiler intrinsics ONLY (R9/R10 lesson: inline-asm DPP
// is invisible to the hazard recognizer -> RA copies corrupt it).
template <int CTRL>
__device__ __forceinline__ float dppf(float v) {
    return __int_as_float(__builtin_amdgcn_mov_dpp(__float_as_int(v), CTRL, 0xF, 0xF, true));
}
template <int M>
__device__ __forceinline__ float sx(float v) {
    if constexpr (M == 1)       return dppf<0xB1>(v);   // quad_perm [1,0,3,2]
    else if constexpr (M == 2)  return dppf<0x4E>(v);   // quad_perm [2,3,0,1]
    else if constexpr (M == 4)  return dppf<0x1B>(dppf<0x141>(v));
    else                        return dppf<0x128>(v);  // row_ror:8
}

// ---- two-register half-swap primitives (VALU) ----
// gfx950 semantics: pl32(a,b): a' = [a_lo | b_lo], b' = [a_hi | b_hi]
//                   pl16(a,b): per 32-half, a' = [a_q0|b_q0], b' = [a_q1|b_q1]
#if __has_builtin(__builtin_amdgcn_permlane32_swap)
__device__ __forceinline__ void pl32(float& a, float& b) {
    auto r = __builtin_amdgcn_permlane32_swap(__float_as_int(a), __float_as_int(b), false, false);
    a = __int_as_float(r[0]); b = __int_as_float(r[1]);
}
#else
__device__ __forceinline__ void pl32(float& a, float& b) {
    const int lane = threadIdx.x & 63;
    const int xaddr = ((threadIdx.x ^ 32) & 63) << 2;
    const float pa = __int_as_float(__builtin_amdgcn_ds_bpermute(xaddr, __float_as_int(a)));
    const float pb = __int_as_float(__builtin_amdgcn_ds_bpermute(xaddr, __float_as_int(b)));
    const bool hi = (lane & 32) != 0;
    const float na = hi ? pb : a;
    const float nb = hi ? b  : pa;
    a = na; b = nb;
}
#endif
#if __has_builtin(__builtin_amdgcn_permlane16_swap)
__device__ __forceinline__ void pl16(float& a, float& b) {
    auto r = __builtin_amdgcn_permlane16_swap(__float_as_int(a), __float_as_int(b), false, false);
    a = __int_as_float(r[0]); b = __int_as_float(r[1]);
}
#else
__device__ __forceinline__ void pl16(float& a, float& b) {
    const int lane = threadIdx.x & 63;
    const float pa = __int_as_float(__builtin_amdgcn_ds_swizzle(__float_as_int(a), 0x401F));
    const float pb = __int_as_float(__builtin_amdgcn_ds_swizzle(__float_as_int(b), 0x401F));
    const bool odd = (lane & 16) != 0;
    const float na = odd ? pb : a;
    const float nb = odd ? b  : pa;
    a = na; b = nb;
}
#endif

// sum over the 16-lane row for a PAIR of values (packed adds)
__device__ __forceinline__ v2f rowred2(v2f v) {
    v2f t;
    t.x = dppf<0x128>(v.x); t.y = dppf<0x128>(v.y); v += t;
    t.x = dppf<0x124>(v.x); t.y = dppf<0x124>(v.y); v += t;
    t.x = dppf<0x122>(v.x); t.y = dppf<0x122>(v.y); v += t;
    t.x = dppf<0x121>(v.x); t.y = dppf<0x121>(v.y); v += t;
    return v;
}
// finish wave-64 reduction for 4 row-reduced values; totals broadcast to all
// lanes. Pure permlane/VALU. (Verified lane-by-lane under pl semantics.)
__device__ __forceinline__ void fin4(float& a, float& b, float& c, float& d) {
    pl16(a, b); float z0 = a + b;
    pl16(c, d); float z1 = c + d;
    pl32(z0, z1); float t = z0 + z1;
    float u = t; pl32(t, u);
    b = t; pl16(t, b); a = t;
    d = u; pl16(u, d); c = u;
}
__device__ __forceinline__ void fin2(float& a, float& b) {
    pl16(a, b); float z = a + b;
    float z2 = z; pl32(z, z2); float t = z + z2;
    b = t; pl16(t, b); a = t;
}

__device__ __forceinline__ float tanh_fast(float x) {
    const float e = __expf(2.0f * x);
    return 1.0f - __fdividef(2.0f, e + 1.0f);
}

// One wave64 = one sample. Amp idx = (lane<<4) | r; wires 0..5 = lane bits
// 5..0; w6..w9 = r bits 3..0. State packed: A2[j] = (amp r=2j, amp r=2j+1),
// so r0 = vector component, r1..r3 = j bits 0..2. All gate arithmetic is
// v_pk_*_f32 (2 FLOP/slot); cross-lane (dpp/permlane) stays 32-bit.
// CNOT fusion (validated R3..R11):
//   pre-CNOT+RY : (al,be) = cbit ? ( g, C) : (C, g),  g = tbit ? S : -S
//   RY+post-CNOT: (al,be) = cbit ? (-g, C) : (C, g)
// Even phase: w0, w2+preC12, w4+preC34, w6+preC56, w8+preC78
// Odd  phase: w1+postC01, w3+postC23, w5+postC45, w7+postC67, w9+postC89
// R13: tangent form — uniform C factors fold into F.
// R14/R15: permlane pair-trick for w0/w1.  R16: VOP3P packing throughout.
__global__ __launch_bounds__(256) void dqc_main(
    const float* __restrict__ x,
    const float* __restrict__ W1,
    const float* __restrict__ b1,
    const float* __restrict__ qw,
    const float* __restrict__ W2,
    const float* __restrict__ b2,
    float* __restrict__ out,
    const int B)
{
    // csl per layer (stride 24):
    // [C0,S0,C2,S2,C4,S4,C6,S6,C8,S8,pad2, C1,S1,C3,S3,C5,S5,C7,S7,C9,S9,pad2]
    // tsl per layer (stride 8): [T0,T7,T8,T9, T1,T3,T5, unused]
    __shared__ __align__(16) float csl[QD * 24];
    __shared__ __align__(16) float tsl[QD * 8];

    const int tid = threadIdx.x;
    if (tid < QD * NQ) {
        const int layer = tid / NQ, wire = tid - layer * NQ;
        const float h = qw[tid] * 0.5f;
        const float s = __sinf(h), c = __cosf(h);
        const int pos = layer * 24 + (wire & 1) * 12 + (wire >> 1) * 2;
        csl[pos] = c; csl[pos + 1] = s;
        int slot = -1;
        if (wire == 0) slot = 0; else if (wire == 7) slot = 1;
        else if (wire == 8) slot = 2; else if (wire == 9) slot = 3;
        else if (wire == 1) slot = 4; else if (wire == 3) slot = 5;
        else if (wire == 5) slot = 6;
        if (slot >= 0) tsl[layer * 8 + slot] = __fdividef(s, c);
    }

    const int lane = tid & 63;
    const int b = blockIdx.x * 4 + (tid >> 6);
    const int bb = (b < B) ? b : (B - 1);

    // ---------- front-end: dot = x[b,:] @ W1 (packed pairs) ----------
    float xr[8];
    {
        const float4* xp = (const float4*)(x + (size_t)bb * DIN + lane * 8);
        const float4 v0 = xp[0], v1 = xp[1];
        xr[0]=v0.x; xr[1]=v0.y; xr[2]=v0.z; xr[3]=v0.w;
        xr[4]=v1.x; xr[5]=v1.y; xr[6]=v1.z; xr[7]=v1.w;
    }
    v2f dv[5];
    #pragma unroll
    for (int m = 0; m < 5; ++m) dv[m] = mk2(0.f, 0.f);
    {
        const float4* wp = (const float4*)(W1 + (size_t)lane * 8 * NQ);
        #pragma unroll
        for (int j = 0; j < 4; ++j) {
            const float4 f0 = wp[5*j], f1 = wp[5*j+1], f2 = wp[5*j+2],
                         f3 = wp[5*j+3], f4 = wp[5*j+4];
            const v2f xa = mk2(xr[2*j], xr[2*j]), xb = mk2(xr[2*j+1], xr[2*j+1]);
            dv[0] = pkfma(xa, mk2(f0.x, f0.y), dv[0]);
            dv[1] = pkfma(xa, mk2(f0.z, f0.w), dv[1]);
            dv[2] = pkfma(xa, mk2(f1.x, f1.y), dv[2]);
            dv[3] = pkfma(xa, mk2(f1.z, f1.w), dv[3]);
            dv[4] = pkfma(xa, mk2(f2.x, f2.y), dv[4]);
            dv[0] = pkfma(xb, mk2(f2.z, f2.w), dv[0]);
            dv[1] = pkfma(xb, mk2(f3.x, f3.y), dv[1]);
            dv[2] = pkfma(xb, mk2(f3.z, f3.w), dv[2]);
            dv[3] = pkfma(xb, mk2(f4.x, f4.y), dv[3]);
            dv[4] = pkfma(xb, mk2(f4.z, f4.w), dv[4]);
        }
    }
    float dot[NQ];
    #pragma unroll
    for (int m = 0; m < 5; ++m) {
        const v2f t = rowred2(dv[m]);
        dot[2*m] = t.x; dot[2*m+1] = t.y;
    }
    fin4(dot[0], dot[1], dot[2], dot[3]);
    fin4(dot[4], dot[5], dot[6], dot[7]);
    fin2(dot[8], dot[9]);

    // u0 = cos(th2+pi/4), u1 = sin(th2+pi/4), th2 = tanh(dot+b1)*pi/4
    float u0[NQ], u1[NQ];
    #pragma unroll
    for (int w = 0; w < NQ; ++w) {
        const float phi = fmaf(tanh_fast(dot[w] + b1[w]),
                               0.78539816339744830962f, 0.78539816339744830962f);
        u0[w] = __cosf(phi);
        u1[w] = __sinf(phi);
    }

    __syncthreads();  // csl/tsl ready (no early return above)

    // ---------- extracted factor F = prod of C over t-form gates ----------
    float F = 1.f;
    #pragma unroll
    for (int k = 0; k < QD; ++k) {
        const float* ce = csl + k * 24;
        F *= ce[0] * ce[18];    // C0 * C7
        F *= ce[8] * ce[20];    // C8 * C9
        F *= ce[12];            // C1 (w1 t-form in EVERY layer)
    }
    {   const float* c5 = csl + 5 * 24;
        F *= c5[14] * c5[16];   // C3 * C5 (last layer no-fuse t-form)
    }

    // ---------- initial product state, E_0 relabel + F folded ----------
    v2f A2[8];
    {
        float lf = ((lane & 32) ? u1[0] : u0[0]);
        lf *= ((((lane >> 4) ^ (lane >> 5)) & 1) ? u1[1] : u0[1]);
        lf *= ((lane & 8) ? u1[2] : u0[2]);
        lf *= ((((lane >> 2) ^ (lane >> 3)) & 1) ? u1[3] : u0[3]);
        lf *= ((lane & 2) ? u1[4] : u0[4]);
        lf *= (((lane ^ (lane >> 1)) & 1) ? u1[5] : u0[5]);
        lf *= F;
        float d1[2] = { lf * u0[6], lf * u1[6] };
        float d2[4], d3[8];
        #pragma unroll
        for (int i = 0; i < 4; ++i) {
            const int r3 = i >> 1, r2 = i & 1;
            d2[i] = d1[r3] * (((r2 ^ r3) & 1) ? u1[7] : u0[7]);
        }
        #pragma unroll
        for (int i = 0; i < 8; ++i)
            d3[i] = d2[i >> 1] * ((i & 1) ? u1[8] : u0[8]);
        const v2f u9a = mk2(u0[9], u1[9]);      // r1 = 0
        const v2f u9b = mk2(u1[9], u0[9]);      // r1 = 1
        #pragma unroll
        for (int i = 0; i < 8; ++i)
            A2[i] = mk2(d3[i], d3[i]) * ((i & 1) ? u9b : u9a);
    }

    // ---------- 6 fused layers ----------
    #pragma unroll 1
    for (int k = 0; k < QD; ++k) {
        const float* ce = csl + k * 24;
        const float4 ea = *(const float4*)(ce);
        const float4 eb = *(const float4*)(ce + 4);
        const float4 tv = *(const float4*)(tsl + k * 8);
        const float4 tw = *(const float4*)(tsl + k * 8 + 4);
        const float C2=ea.z,S2=ea.w, C4=eb.x,S4=eb.y, C6=eb.z,S6=eb.w;
        const float T0=tv.x, T7=tv.y, T8=tv.z, T9=tv.w;
        const float T1=tw.x;

        // ==== even phase ====
        {   // w0 (t-form): pl32 pair trick; pk_fma between the swaps
            #pragma unroll
            for (int i = 0; i < 8; ++i) {
                float u = A2[i].x, v = A2[i].y;
                pl32(u, v);                              // u=a0, v=a1
                const v2f g = mk2(u, v);
                const v2f n = pkfma(mk2(-T0, T0), swap2(g), g);
                float n0 = n.x, n1 = n.y;
                pl32(n0, n1);
                A2[i] = mk2(n0, n1);
            }
        }
        {   // w2 + pre C(1,2): xor8 (row_ror:8), ctrl lane b4
            const float g = (lane & 8) ? S2 : -S2;
            const bool cb = (lane & 16) != 0;
            const float al = cb ? g : C2, be = cb ? C2 : g;
            const v2f alv = mk2(al, al), bev = mk2(be, be);
            #pragma unroll
            for (int j = 0; j < 8; ++j) {
                const v2f p = mk2(sx<8>(A2[j].x), sx<8>(A2[j].y));
                A2[j] = pkfma(alv, A2[j], bev * p);
            }
        }
        {   // w4 + pre C(3,4): xor2 (quad_perm), ctrl lane b2
            const float g = (lane & 2) ? S4 : -S4;
            const bool cb = (lane & 4) != 0;
            const float al = cb ? g : C4, be = cb ? C4 : g;
            const v2f alv = mk2(al, al), bev = mk2(be, be);
            #pragma unroll
            for (int j = 0; j < 8; ++j) {
                const v2f p = mk2(sx<2>(A2[j].x), sx<2>(A2[j].y));
                A2[j] = pkfma(alv, A2[j], bev * p);
            }
        }
        {   // w6 + pre C(5,6): v2 pairs (j, j+4), ctrl lane b0
            const bool cb = (lane & 1) != 0;
            const float a_lo = cb ? -S6 : C6, b_lo = cb ? C6 : -S6;
            const float a_hi = cb ?  S6 : C6, b_hi = cb ? C6 :  S6;
            const v2f alo = mk2(a_lo, a_lo), blo = mk2(b_lo, b_lo);
            const v2f ahi = mk2(a_hi, a_hi), bhi = mk2(b_hi, b_hi);
            #pragma unroll
            for (int j = 0; j < 4; ++j) {
                const v2f lo = A2[j], hi = A2[j + 4];
                A2[j]     = pkfma(alo, lo, blo * hi);
                A2[j + 4] = pkfma(ahi, hi, bhi * lo);
            }
        }
        {   // w8 + pre C(7,8) (t-form): v2 pairs (2m, 2m+1), sign by m&1
            const v2f tp = mk2(T8, T8), tn = mk2(-T8, -T8);
            #pragma unroll
            for (int m = 0; m < 4; ++m) {
                const v2f lo = A2[2*m], hi = A2[2*m + 1];
                if (m & 1) {
                    A2[2*m]     = pkfma(tn, lo, hi);
                    A2[2*m + 1] = pkfma(tp, hi, lo);
                } else {
                    A2[2*m]     = pkfma(tn, hi, lo);
                    A2[2*m + 1] = pkfma(tp, lo, hi);
                }
            }
        }

        // ==== odd phase ====
        if (k != QD - 1) {
            const float4 oa = *(const float4*)(ce + 12);
            const float2 ob = *(const float2*)(ce + 16);
            const float C3=oa.z,S3=oa.w, C5=ob.x,S5=ob.y;

            {   // w1 + post C(0,1) (t-form): pl16 pair trick, ctrl lane b5.
                // cb is uniform per 32-half -> divergent branch, permlanes
                // OUTSIDE the branch (convergent).
                v2f g[8];
                #pragma unroll
                for (int i = 0; i < 8; ++i) {
                    float u = A2[i].x, v = A2[i].y;
                    pl16(u, v);
                    g[i] = mk2(u, v);
                }
                if (lane & 32) {
                    const v2f t = mk2(T1, -T1);
                    #pragma unroll
                    for (int i = 0; i < 8; ++i) g[i] = pkfma(t, g[i], swap2(g[i]));  // (q1,q0)
                } else {
                    const v2f t = mk2(-T1, T1);
                    #pragma unroll
                    for (int i = 0; i < 8; ++i) g[i] = pkfma(t, swap2(g[i]), g[i]);  // (q0,q1)
                }
                #pragma unroll
                for (int i = 0; i < 8; ++i) {
                    float u = g[i].x, v = g[i].y;
                    pl16(u, v);
                    A2[i] = mk2(u, v);
                }
            }
            {   // w3 + post C(2,3): xor4, ctrl lane b3
                const float g = (lane & 4) ? S3 : -S3;
                const bool cb = (lane & 8) != 0;
                const float al = cb ? -g : C3, be = cb ? C3 : g;
                const v2f alv = mk2(al, al), bev = mk2(be, be);
                #pragma unroll
                for (int j = 0; j < 8; ++j) {
                    const v2f p = mk2(sx<4>(A2[j].x), sx<4>(A2[j].y));
                    A2[j] = pkfma(alv, A2[j], bev * p);
                }
            }
            {   // w5 + post C(4,5): xor1, ctrl lane b1
                const float g = (lane & 1) ? S5 : -S5;
                const bool cb = (lane & 2) != 0;
                const float al = cb ? -g : C5, be = cb ? C5 : g;
                const v2f alv = mk2(al, al), bev = mk2(be, be);
                #pragma unroll
                for (int j = 0; j < 8; ++j) {
                    const v2f p = mk2(sx<1>(A2[j].x), sx<1>(A2[j].y));
                    A2[j] = pkfma(alv, A2[j], bev * p);
                }
            }
            {   // w7 + post C(6,7) (t-form, fuse): v2 pairs (j, j+2), sign j&4
                const v2f tp = mk2(T7, T7), tn = mk2(-T7, -T7);
                #pragma unroll
                for (int j = 0; j < 2; ++j) {
                    const v2f lo = A2[j], hi = A2[j + 2];
                    A2[j]     = pkfma(tn, hi, lo);
                    A2[j + 2] = pkfma(tp, lo, hi);
                }
                #pragma unroll
                for (int j = 4; j < 6; ++j) {
                    const v2f lo = A2[j], hi = A2[j + 2];
                    A2[j]     = pkfma(tp, lo, hi);
                    A2[j + 2] = pkfma(tn, hi, lo);
                }
            }
            {   // w9 + post C(8,9) (t-form, fuse): in-vector, sign by j&1
                const v2f ta = mk2(-T9, T9), tb = mk2(T9, -T9);
                #pragma unroll
                for (int j = 0; j < 8; ++j) {
                    const v2f v = A2[j];
                    A2[j] = (j & 1) ? pkfma(tb, v, swap2(v))
                                    : pkfma(ta, swap2(v), v);
                }
            }
        } else {
            // last layer: no post-CNOT anywhere -> all plain RY, all t-form
            const float T3 = tw.y, T5 = tw.z;

            {   // w1: pl16 pair trick, no CNOT
                const v2f t = mk2(-T1, T1);
                #pragma unroll
                for (int i = 0; i < 8; ++i) {
                    float u = A2[i].x, v = A2[i].y;
                    pl16(u, v);
                    const v2f g = mk2(u, v);
                    const v2f n = pkfma(t, swap2(g), g);
                    float n0 = n.x, n1 = n.y;
                    pl16(n0, n1);
                    A2[i] = mk2(n0, n1);
                }
            }
            {   // w3: xor4
                const float t3 = (lane & 4) ? T3 : -T3;
                const v2f t3v = mk2(t3, t3);
                #pragma unroll
                for (int j = 0; j < 8; ++j) {
                    const v2f p = mk2(sx<4>(A2[j].x), sx<4>(A2[j].y));
                    A2[j] = pkfma(t3v, p, A2[j]);
                }
            }
            {   // w5: xor1
                const float t5 = (lane & 1) ? T5 : -T5;
                const v2f t5v = mk2(t5, t5);
                #pragma unroll
                for (int j = 0; j < 8; ++j) {
                    const v2f p = mk2(sx<1>(A2[j].x), sx<1>(A2[j].y));
                    A2[j] = pkfma(t5v, p, A2[j]);
                }
            }
            {   // w7 (t-form, no fuse): v2 pairs (j, j+2)
                const v2f tp = mk2(T7, T7), tn = mk2(-T7, -T7);
                #pragma unroll
                for (int j = 0; j < 2; ++j) {
                    const v2f lo = A2[j], hi = A2[j + 2];
                    A2[j]     = pkfma(tn, hi, lo);
                    A2[j + 2] = pkfma(tp, lo, hi);
                }
                #pragma unroll
                for (int j = 4; j < 6; ++j) {
                    const v2f lo = A2[j], hi = A2[j + 2];
                    A2[j]     = pkfma(tn, hi, lo);
                    A2[j + 2] = pkfma(tp, lo, hi);
                }
            }
            {   // w9 (t-form, no fuse): in-vector
                const v2f ta = mk2(-T9, T9);
                #pragma unroll
                for (int j = 0; j < 8; ++j) {
                    const v2f v = A2[j];
                    A2[j] = pkfma(ta, swap2(v), v);
                }
            }
        }
    }

    // ---------- expvals <Z_w> (packed prob sums) ----------
    v2f tot2 = mk2(0.f, 0.f), s6 = mk2(0.f, 0.f),
        s7 = mk2(0.f, 0.f), s8 = mk2(0.f, 0.f);
    #pragma unroll
    for (int j = 0; j < 8; ++j) {
        const v2f P = A2[j] * A2[j];
        tot2 += P;
        if (j & 4) s6 += P;
        if (j & 2) s7 += P;
        if (j & 1) s8 += P;
    }
    const float tot = tot2.x + tot2.y;
    const float q6 = s6.x + s6.y;
    const float q7 = s7.x + s7.y;
    const float q8 = s8.x + s8.y;
    const float q9 = tot2.y;              // odd r == odd component

    float e[NQ];
    e[0] = (lane & 32) ? -tot : tot;
    e[1] = (lane & 16) ? -tot : tot;
    e[2] = (lane & 8)  ? -tot : tot;
    e[3] = (lane & 4)  ? -tot : tot;
    e[4] = (lane & 2)  ? -tot : tot;
    e[5] = (lane & 1)  ? -tot : tot;
    e[6] = fmaf(-2.f, q6, tot);
    e[7] = fmaf(-2.f, q7, tot);
    e[8] = fmaf(-2.f, q8, tot);
    e[9] = fmaf(-2.f, q9, tot);
    #pragma unroll
    for (int m = 0; m < 5; ++m) {
        const v2f t = rowred2(mk2(e[2*m], e[2*m+1]));
        e[2*m] = t.x; e[2*m+1] = t.y;
    }
    fin4(e[0], e[1], e[2], e[3]);
    fin4(e[4], e[5], e[6], e[7]);
    fin2(e[8], e[9]);

    // ---------- output GEMM: lane = output column ----------
    if (b < B) {
        float o = b2[lane];
        #pragma unroll
        for (int w = 0; w < NQ; ++w) o = fmaf(e[w], W2[w * DOUT + lane], o);
        out[(size_t)b * DOUT + lane] = o;
    }
}

extern "C" void kernel_launch(void* const* d_in, const int* in_sizes, int n_in,
                              void* d_out, int out_size, void* d_ws, size_t ws_size,
                              hipStream_t stream) {
    const float* x  = (const float*)d_in[0];
    const float* W1 = (const float*)d_in[1];
    const float* b1 = (const float*)d_in[2];
    const float* qw = (const float*)d_in[3];
    const float* W2 = (const float*)d_in[4];
    const float* b2 = (const float*)d_in[5];
    float* out = (float*)d_out;

    const int B = in_sizes[0] / DIN;
    const int blocks = (B + 3) / 4;   // 4 samples (waves) per 256-thread block
    dqc_main<<<blocks, 256, 0, stream>>>(x, W1, b1, qw, W2, b2, out, B);
}

// Round 4
// 100.692 us; speedup vs baseline: 1.0730x; 1.0730x over previous
//
#include <hip/hip_runtime.h>

#define NQ 10
#define QD 6
#define DIN 512
#define DOUT 64

// All cross-lane via compiler intrinsics ONLY (R9/R10 lesson: inline-asm DPP
// is invisible to the hazard recognizer -> RA copies corrupt it).
template <int CTRL>
__device__ __forceinline__ float dppf(float v) {
    return __int_as_float(__builtin_amdgcn_mov_dpp(__float_as_int(v), CTRL, 0xF, 0xF, true));
}
// LDS-pipe xor-shuffle within 32-lane halves (frees VALU issue slots — R4).
// masks: xor1=0x041F xor2=0x081F xor4=0x101F xor8=0x201F xor16=0x401F
template <int MASK>
__device__ __forceinline__ float swz(float v) {
    return __int_as_float(__builtin_amdgcn_ds_swizzle(__float_as_int(v), MASK));
}
__device__ __forceinline__ float bperm(float v, int xaddr) {
    return __int_as_float(__builtin_amdgcn_ds_bpermute(xaddr, __float_as_int(v)));
}

// ---- two-register half-swap primitives (VALU; for reduction finishers) ----
// gfx950 semantics: pl32(a,b): a' = [a_lo | b_lo], b' = [a_hi | b_hi]
//                   pl16(a,b): per 32-half, a' = [a_q0|b_q0], b' = [a_q1|b_q1]
#if __has_builtin(__builtin_amdgcn_permlane32_swap)
__device__ __forceinline__ void pl32(float& a, float& b) {
    auto r = __builtin_amdgcn_permlane32_swap(__float_as_int(a), __float_as_int(b), false, false);
    a = __int_as_float(r[0]); b = __int_as_float(r[1]);
}
#else
__device__ __forceinline__ void pl32(float& a, float& b) {
    const int lane = threadIdx.x & 63;
    const int xaddr = ((threadIdx.x ^ 32) & 63) << 2;
    const float pa = bperm(a, xaddr);
    const float pb = bperm(b, xaddr);
    const bool hi = (lane & 32) != 0;
    const float na = hi ? pb : a;
    const float nb = hi ? b  : pa;
    a = na; b = nb;
}
#endif
#if __has_builtin(__builtin_amdgcn_permlane16_swap)
__device__ __forceinline__ void pl16(float& a, float& b) {
    auto r = __builtin_amdgcn_permlane16_swap(__float_as_int(a), __float_as_int(b), false, false);
    a = __int_as_float(r[0]); b = __int_as_float(r[1]);
}
#else
__device__ __forceinline__ void pl16(float& a, float& b) {
    const int lane = threadIdx.x & 63;
    const float pa = swz<0x401F>(a);
    const float pb = swz<0x401F>(b);
    const bool odd = (lane & 16) != 0;
    const float na = odd ? pb : a;
    const float nb = odd ? b  : pa;
    a = na; b = nb;
}
#endif

// sum over the 16-lane row, result broadcast within the row (DPP only)
__device__ __forceinline__ float rowred(float v) {
    v += dppf<0x128>(v); v += dppf<0x124>(v);
    v += dppf<0x122>(v); v += dppf<0x121>(v);
    return v;
}
// finish wave-64 reduction for 4 row-reduced values; totals broadcast to all
// lanes. Pure permlane/VALU. (Validated R2.)
__device__ __forceinline__ void fin4(float& a, float& b, float& c, float& d) {
    pl16(a, b); float z0 = a + b;
    pl16(c, d); float z1 = c + d;
    pl32(z0, z1); float t = z0 + z1;
    float u = t; pl32(t, u);
    b = t; pl16(t, b); a = t;
    d = u; pl16(u, d); c = u;
}
__device__ __forceinline__ void fin2(float& a, float& b) {
    pl16(a, b); float z = a + b;
    float z2 = z; pl32(z, z2); float t = z + z2;
    b = t; pl16(t, b); a = t;
}

__device__ __forceinline__ float tanh_fast(float x) {
    const float e = __expf(2.0f * x);
    return 1.0f - __fdividef(2.0f, e + 1.0f);
}

// One wave64 = one sample. Amp idx = (lane<<4) | r; wires 0..5 = lane bits
// 5..0; w6..w9 = r bits 3..0.
// CNOT fusion (validated R3..R11):
//   pre-CNOT+RY : (al,be) = cbit ? ( g, C) : (C, g),  g = tbit ? S : -S
//   RY+post-CNOT: (al,be) = cbit ? (-g, C) : (C, g)
// Even phase: w0, w2+preC12, w4+preC34, w6+preC56, w8+preC78
// Odd  phase: w1+postC01, w3+postC23, w5+postC45, w7+postC67, w9+postC89
// R13: tangent form — uniform C factors fold into F (w0,w7,w8,w9 all layers;
// w1,w3,w5 last layer).
// R4 (this round): pipe rebalance. All xor-type lane-gate shuffles go on the
// LDS pipe (ds_swizzle/ds_bpermute, 1 issue) instead of VALU DPP/permlane;
// VALU keeps only the irreducible mul/fma stream. R0 gate algebra restored.
__global__ __launch_bounds__(256) void dqc_main(
    const float* __restrict__ x,
    const float* __restrict__ W1,
    const float* __restrict__ b1,
    const float* __restrict__ qw,
    const float* __restrict__ W2,
    const float* __restrict__ b2,
    float* __restrict__ out,
    const int B)
{
    // csl per layer (stride 24):
    // [C0,S0,C2,S2,C4,S4,C6,S6,C8,S8,pad2, C1,S1,C3,S3,C5,S5,C7,S7,C9,S9,pad2]
    // tsl per layer (stride 8): [T0,T7,T8,T9, T1,T3,T5, unused]
    __shared__ __align__(16) float csl[QD * 24];
    __shared__ __align__(16) float tsl[QD * 8];

    const int tid = threadIdx.x;
    if (tid < QD * NQ) {
        const int layer = tid / NQ, wire = tid - layer * NQ;
        const float h = qw[tid] * 0.5f;
        const float s = __sinf(h), c = __cosf(h);
        const int pos = layer * 24 + (wire & 1) * 12 + (wire >> 1) * 2;
        csl[pos] = c; csl[pos + 1] = s;
        int slot = -1;
        if (wire == 0) slot = 0; else if (wire == 7) slot = 1;
        else if (wire == 8) slot = 2; else if (wire == 9) slot = 3;
        else if (wire == 1) slot = 4; else if (wire == 3) slot = 5;
        else if (wire == 5) slot = 6;
        if (slot >= 0) tsl[layer * 8 + slot] = __fdividef(s, c);
    }

    const int lane = tid & 63;
    const int b = blockIdx.x * 4 + (tid >> 6);
    const int bb = (b < B) ? b : (B - 1);
    const int xaddr = ((tid ^ 32) & 63) << 2;   // bpermute addr: lane^32

    // ---------- front-end: dot = x[b,:] @ W1 ----------
    float xr[8];
    {
        const float4* xp = (const float4*)(x + (size_t)bb * DIN + lane * 8);
        const float4 v0 = xp[0], v1 = xp[1];
        xr[0]=v0.x; xr[1]=v0.y; xr[2]=v0.z; xr[3]=v0.w;
        xr[4]=v1.x; xr[5]=v1.y; xr[6]=v1.z; xr[7]=v1.w;
    }
    float dot[NQ];
    #pragma unroll
    for (int w = 0; w < NQ; ++w) dot[w] = 0.f;
    {
        const float4* wp = (const float4*)(W1 + (size_t)lane * 8 * NQ);
        #pragma unroll
        for (int j = 0; j < 4; ++j) {
            const float4 f0 = wp[5*j], f1 = wp[5*j+1], f2 = wp[5*j+2],
                         f3 = wp[5*j+3], f4 = wp[5*j+4];
            const float xa = xr[2*j], xb = xr[2*j+1];
            dot[0]=fmaf(xa,f0.x,dot[0]); dot[1]=fmaf(xa,f0.y,dot[1]);
            dot[2]=fmaf(xa,f0.z,dot[2]); dot[3]=fmaf(xa,f0.w,dot[3]);
            dot[4]=fmaf(xa,f1.x,dot[4]); dot[5]=fmaf(xa,f1.y,dot[5]);
            dot[6]=fmaf(xa,f1.z,dot[6]); dot[7]=fmaf(xa,f1.w,dot[7]);
            dot[8]=fmaf(xa,f2.x,dot[8]); dot[9]=fmaf(xa,f2.y,dot[9]);
            dot[0]=fmaf(xb,f2.z,dot[0]); dot[1]=fmaf(xb,f2.w,dot[1]);
            dot[2]=fmaf(xb,f3.x,dot[2]); dot[3]=fmaf(xb,f3.y,dot[3]);
            dot[4]=fmaf(xb,f3.z,dot[4]); dot[5]=fmaf(xb,f3.w,dot[5]);
            dot[6]=fmaf(xb,f4.x,dot[6]); dot[7]=fmaf(xb,f4.y,dot[7]);
            dot[8]=fmaf(xb,f4.z,dot[8]); dot[9]=fmaf(xb,f4.w,dot[9]);
        }
    }
    #pragma unroll
    for (int w = 0; w < NQ; ++w) dot[w] = rowred(dot[w]);
    fin4(dot[0], dot[1], dot[2], dot[3]);
    fin4(dot[4], dot[5], dot[6], dot[7]);
    fin2(dot[8], dot[9]);

    // u0 = cos(th2+pi/4), u1 = sin(th2+pi/4), th2 = tanh(dot+b1)*pi/4
    float u0[NQ], u1[NQ];
    #pragma unroll
    for (int w = 0; w < NQ; ++w) {
        const float phi = fmaf(tanh_fast(dot[w] + b1[w]),
                               0.78539816339744830962f, 0.78539816339744830962f);
        u0[w] = __cosf(phi);
        u1[w] = __sinf(phi);
    }

    __syncthreads();  // csl/tsl ready (no early return above)

    // ---------- extracted factor F = prod of C over t-form gates ----------
    float F = 1.f;
    #pragma unroll
    for (int k = 0; k < QD; ++k) {
        const float* ce = csl + k * 24;
        F *= ce[0] * ce[18];    // C0 * C7
        F *= ce[8] * ce[20];    // C8 * C9
    }
    {   const float* c5 = csl + 5 * 24;
        F *= c5[12] * c5[14];   // C1 * C3 (last layer no-fuse t-form)
        F *= c5[16];            // C5
    }

    // ---------- initial product state, E_0 relabel + F folded ----------
    float A[16];
    {
        float lf = ((lane & 32) ? u1[0] : u0[0]);
        lf *= ((((lane >> 4) ^ (lane >> 5)) & 1) ? u1[1] : u0[1]);
        lf *= ((lane & 8) ? u1[2] : u0[2]);
        lf *= ((((lane >> 2) ^ (lane >> 3)) & 1) ? u1[3] : u0[3]);
        lf *= ((lane & 2) ? u1[4] : u0[4]);
        lf *= (((lane ^ (lane >> 1)) & 1) ? u1[5] : u0[5]);
        lf *= F;
        float d1[2] = { lf * u0[6], lf * u1[6] };
        float d2[4], d3[8];
        #pragma unroll
        for (int i = 0; i < 4; ++i) {
            const int r3 = i >> 1, r2 = i & 1;
            d2[i] = d1[r3] * (((r2 ^ r3) & 1) ? u1[7] : u0[7]);
        }
        #pragma unroll
        for (int i = 0; i < 8; ++i)
            d3[i] = d2[i >> 1] * ((i & 1) ? u1[8] : u0[8]);
        #pragma unroll
        for (int i = 0; i < 8; ++i) {
            const int r1 = i & 1;
            A[2*i]   = d3[i] * (r1 ? u1[9] : u0[9]);   // r0=0: r0^r1 = r1
            A[2*i+1] = d3[i] * (r1 ? u0[9] : u1[9]);   // r0=1: r0^r1 = !r1
        }
    }

    // ---------- 6 fused layers ----------
    #pragma unroll 1
    for (int k = 0; k < QD; ++k) {
        const float* ce = csl + k * 24;
        const float4 ea = *(const float4*)(ce);
        const float4 eb = *(const float4*)(ce + 4);
        const float4 tv = *(const float4*)(tsl + k * 8);
        const float C2=ea.z,S2=ea.w, C4=eb.x,S4=eb.y, C6=eb.z,S6=eb.w;
        const float T0=tv.x, T7=tv.y, T8=tv.z, T9=tv.w;

        // ==== even phase ====
        {   // w0 (t-form): partner lane^32 via bpermute (LDS pipe)
            const float t0 = (lane & 32) ? T0 : -T0;
            float p[16];
            #pragma unroll
            for (int r = 0; r < 16; ++r) p[r] = bperm(A[r], xaddr);
            #pragma unroll
            for (int r = 0; r < 16; ++r) A[r] = fmaf(t0, p[r], A[r]);
        }
        {   // w2 + pre C(1,2): xor8 via ds_swizzle, ctrl lane b4
            const float g = (lane & 8) ? S2 : -S2;
            const bool cb = (lane & 16) != 0;
            const float al = cb ? g : C2, be = cb ? C2 : g;
            #pragma unroll
            for (int r = 0; r < 16; ++r) A[r] = fmaf(al, A[r], be * swz<0x201F>(A[r]));
        }
        {   // w4 + pre C(3,4): xor2 via ds_swizzle, ctrl lane b2
            const float g = (lane & 2) ? S4 : -S4;
            const bool cb = (lane & 4) != 0;
            const float al = cb ? g : C4, be = cb ? C4 : g;
            #pragma unroll
            for (int r = 0; r < 16; ++r) A[r] = fmaf(al, A[r], be * swz<0x081F>(A[r]));
        }
        {   // w6 + pre C(5,6): reg pairs (r, r+8), ctrl lane b0 (runtime)
            const bool cb = (lane & 1) != 0;
            const float a_lo = cb ? -S6 : C6, b_lo = cb ? C6 : -S6;
            const float a_hi = cb ?  S6 : C6, b_hi = cb ? C6 :  S6;
            #pragma unroll
            for (int r = 0; r < 8; ++r) {
                const float lo = A[r], hi = A[r + 8];
                A[r]     = fmaf(a_lo, lo, b_lo * hi);
                A[r + 8] = fmaf(a_hi, hi, b_hi * lo);
            }
        }
        {   // w8 + pre C(7,8) (t-form): reg pairs (r, r+2), ctrl r bit2
            #pragma unroll
            for (int r = 0; r < 16; ++r) {
                if (r & 2) continue;
                const float lo = A[r], hi = A[r + 2];
                if (r & 4) {
                    A[r]     = fmaf(-T8, lo, hi);
                    A[r + 2] = fmaf( T8, hi, lo);
                } else {
                    A[r]     = fmaf(-T8, hi, lo);
                    A[r + 2] = fmaf( T8, lo, hi);
                }
            }
        }

        // ==== odd phase ====
        if (k != QD - 1) {
            const float4 oa = *(const float4*)(ce + 12);
            const float2 ob = *(const float2*)(ce + 16);
            const float C1=oa.x,S1=oa.y, C3=oa.z,S3=oa.w, C5=ob.x,S5=ob.y;

            {   // w1 + post C(0,1): xor16 via ds_swizzle, ctrl lane b5
                const float g = (lane & 16) ? S1 : -S1;
                const bool cb = (lane & 32) != 0;
                const float al = cb ? -g : C1, be = cb ? C1 : g;
                float p[16];
                #pragma unroll
                for (int r = 0; r < 16; ++r) p[r] = swz<0x401F>(A[r]);
                #pragma unroll
                for (int r = 0; r < 16; ++r) A[r] = fmaf(al, A[r], be * p[r]);
            }
            {   // w3 + post C(2,3): xor4 via ds_swizzle, ctrl lane b3
                const float g = (lane & 4) ? S3 : -S3;
                const bool cb = (lane & 8) != 0;
                const float al = cb ? -g : C3, be = cb ? C3 : g;
                #pragma unroll
                for (int r = 0; r < 16; ++r) A[r] = fmaf(al, A[r], be * swz<0x101F>(A[r]));
            }
            {   // w5 + post C(4,5): xor1 via ds_swizzle, ctrl lane b1
                const float g = (lane & 1) ? S5 : -S5;
                const bool cb = (lane & 2) != 0;
                const float al = cb ? -g : C5, be = cb ? C5 : g;
                #pragma unroll
                for (int r = 0; r < 16; ++r) A[r] = fmaf(al, A[r], be * swz<0x041F>(A[r]));
            }
            {   // w7 + post C(6,7) (t-form, fuse): pairs (r, r+4), ctrl r bit3
                #pragma unroll
                for (int r = 0; r < 16; ++r) {
                    if (r & 4) continue;
                    const float lo = A[r], hi = A[r + 4];
                    if (r & 8) {
                        A[r]     = fmaf( T7, lo, hi);
                        A[r + 4] = fmaf(-T7, hi, lo);
                    } else {
                        A[r]     = fmaf(-T7, hi, lo);
                        A[r + 4] = fmaf( T7, lo, hi);
                    }
                }
            }
            {   // w9 + post C(8,9) (t-form, fuse): pairs (r, r+1), ctrl r bit1
                #pragma unroll
                for (int r = 0; r < 16; r += 2) {
                    const float xv = A[r], yv = A[r + 1];
                    if (r & 2) {
                        A[r]     = fmaf( T9, xv, yv);
                        A[r + 1] = fmaf(-T9, yv, xv);
                    } else {
                        A[r]     = fmaf(-T9, yv, xv);
                        A[r + 1] = fmaf( T9, xv, yv);
                    }
                }
            }
        } else {
            // last layer: no post-CNOT anywhere -> all plain RY, all t-form
            const float4 tv2 = *(const float4*)(tsl + k * 8 + 4);
            const float T1 = tv2.x, T3 = tv2.y, T5 = tv2.z;

            {   // w1: xor16 via ds_swizzle
                const float t1 = (lane & 16) ? T1 : -T1;
                float p[16];
                #pragma unroll
                for (int r = 0; r < 16; ++r) p[r] = swz<0x401F>(A[r]);
                #pragma unroll
                for (int r = 0; r < 16; ++r) A[r] = fmaf(t1, p[r], A[r]);
            }
            {   // w3: xor4 via ds_swizzle
                const float t3 = (lane & 4) ? T3 : -T3;
                #pragma unroll
                for (int r = 0; r < 16; ++r) A[r] = fmaf(t3, swz<0x101F>(A[r]), A[r]);
            }
            {   // w5: xor1 via ds_swizzle
                const float t5 = (lane & 1) ? T5 : -T5;
                #pragma unroll
                for (int r = 0; r < 16; ++r) A[r] = fmaf(t5, swz<0x041F>(A[r]), A[r]);
            }
            {   // w7 (t-form, no fuse)
                #pragma unroll
                for (int r = 0; r < 16; ++r) {
                    if (r & 4) continue;
                    const float lo = A[r], hi = A[r + 4];
                    A[r]     = fmaf(-T7, hi, lo);
                    A[r + 4] = fmaf( T7, lo, hi);
                }
            }
            {   // w9 (t-form, no fuse)
                #pragma unroll
                for (int r = 0; r < 16; r += 2) {
                    const float xv = A[r], yv = A[r + 1];
                    A[r]     = fmaf(-T9, yv, xv);
                    A[r + 1] = fmaf( T9, xv, yv);
                }
            }
        }
    }

    // ---------- expvals <Z_w> ----------
    float tot = 0.f, q6 = 0.f, q7 = 0.f, q8 = 0.f, q9 = 0.f;
    #pragma unroll
    for (int r = 0; r < 16; ++r) {
        const float P = A[r] * A[r];
        tot += P;
        if (r & 8) q6 += P;
        if (r & 4) q7 += P;
        if (r & 2) q8 += P;
        if (r & 1) q9 += P;
    }
    float e[NQ];
    e[0] = (lane & 32) ? -tot : tot;
    e[1] = (lane & 16) ? -tot : tot;
    e[2] = (lane & 8)  ? -tot : tot;
    e[3] = (lane & 4)  ? -tot : tot;
    e[4] = (lane & 2)  ? -tot : tot;
    e[5] = (lane & 1)  ? -tot : tot;
    e[6] = fmaf(-2.f, q6, tot);
    e[7] = fmaf(-2.f, q7, tot);
    e[8] = fmaf(-2.f, q8, tot);
    e[9] = fmaf(-2.f, q9, tot);
    #pragma unroll
    for (int w = 0; w < NQ; ++w) e[w] = rowred(e[w]);
    fin4(e[0], e[1], e[2], e[3]);
    fin4(e[4], e[5], e[6], e[7]);
    fin2(e[8], e[9]);

    // ---------- output GEMM: lane = output column ----------
    if (b < B) {
        float o = b2[lane];
        #pragma unroll
        for (int w = 0; w < NQ; ++w) o = fmaf(e[w], W2[w * DOUT + lane], o);
        out[(size_t)b * DOUT + lane] = o;
    }
}

extern "C" void kernel_launch(void* const* d_in, const int* in_sizes, int n_in,
                              void* d_out, int out_size, void* d_ws, size_t ws_size,
                              hipStream_t stream) {
    const float* x  = (const float*)d_in[0];
    const float* W1 = (const float*)d_in[1];
    const float* b1 = (const float*)d_in[2];
    const float* qw = (const float*)d_in[3];
    const float* W2 = (const float*)d_in[4];
    const float* b2 = (const float*)d_in[5];
    float* out = (float*)d_out;

    const int B = in_sizes[0] / DIN;
    const int blocks = (B + 3) / 4;   // 4 samples (waves) per 256-thread block
    dqc_main<<<blocks, 256, 0, stream>>>(x, W1, b1, qw, W2, b2, out, B);
}